// Round 1
// baseline (135.426 us; speedup 1.0000x reference)
//
#include <hip/hip_runtime.h>

#define NB 8          // 7 full blocks + 1 partial block
#define DDIM 2048
#define THREADS 256
#define PER 8         // DDIM / THREADS

__global__ __launch_bounds__(THREADS, 2)
void block_attn_res_kernel(
    const float* __restrict__ blocks,   // [7, B*T, D]
    const float* __restrict__ partial,  // [B*T, D]
    const float* __restrict__ qa,       // [D]
    const float* __restrict__ qm,       // [D]
    const float* __restrict__ wa,       // [D]
    const float* __restrict__ wm,       // [D]
    float* __restrict__ out,            // h_attn [B*T*D] then h_mlp [B*T*D]
    int BT)
{
    const int row = blockIdx.x;
    const int tid = threadIdx.x;
    const int d0  = tid * PER;

    // per-thread q*w slice (weight applied inside the logit dot; rmsnorm cast is a
    // no-op for f32 inputs, so logits = rms * sum_d q[d]*w[d]*V[d] / sqrt(D))
    float qwa[PER], qwm[PER];
#pragma unroll
    for (int j = 0; j < PER; ++j) {
        qwa[j] = qa[d0 + j] * wa[d0 + j];
        qwm[j] = qm[d0 + j] * wm[d0 + j];
    }

    const size_t rowOff   = (size_t)row * DDIM + d0;
    const size_t nStride  = (size_t)BT * DDIM;

    float v[NB][PER];
    float ss[NB], da[NB], dm[NB];

#pragma unroll
    for (int n = 0; n < NB; ++n) {
        const float* src = (n < NB - 1) ? (blocks + (size_t)n * nStride + rowOff)
                                        : (partial + rowOff);
        float4 a = *reinterpret_cast<const float4*>(src);
        float4 b = *reinterpret_cast<const float4*>(src + 4);
        v[n][0] = a.x; v[n][1] = a.y; v[n][2] = a.z; v[n][3] = a.w;
        v[n][4] = b.x; v[n][5] = b.y; v[n][6] = b.z; v[n][7] = b.w;
        float s = 0.f, pa = 0.f, pm = 0.f;
#pragma unroll
        for (int j = 0; j < PER; ++j) {
            s  += v[n][j] * v[n][j];
            pa += qwa[j]  * v[n][j];
            pm += qwm[j]  * v[n][j];
        }
        ss[n] = s; da[n] = pa; dm[n] = pm;
    }

    // 64-lane wave reduction of the 24 partials
#pragma unroll
    for (int n = 0; n < NB; ++n) {
#pragma unroll
        for (int off = 32; off > 0; off >>= 1) {
            ss[n] += __shfl_down(ss[n], off, 64);
            da[n] += __shfl_down(da[n], off, 64);
            dm[n] += __shfl_down(dm[n], off, 64);
        }
    }

    // cross-wave combine via tiny LDS
    __shared__ float red[THREADS / 64][NB * 3];
    const int wave = tid >> 6;
    const int lane = tid & 63;
    if (lane == 0) {
#pragma unroll
        for (int n = 0; n < NB; ++n) {
            red[wave][n]          = ss[n];
            red[wave][NB + n]     = da[n];
            red[wave][2 * NB + n] = dm[n];
        }
    }
    __syncthreads();

    float aw[NB], mw[NB];
    {
        const float inv_sqrt_d = rsqrtf((float)DDIM);
        float lga[NB], lgm[NB];
#pragma unroll
        for (int n = 0; n < NB; ++n) {
            float s  = red[0][n] + red[1][n] + red[2][n] + red[3][n];
            float pa = red[0][NB + n] + red[1][NB + n] + red[2][NB + n] + red[3][NB + n];
            float pm = red[0][2 * NB + n] + red[1][2 * NB + n] + red[2][2 * NB + n] + red[3][2 * NB + n];
            float rms = rsqrtf(s * (1.0f / DDIM) + 1e-6f);
            lga[n] = pa * rms * inv_sqrt_d;
            lgm[n] = pm * rms * inv_sqrt_d;
        }
        float ma = lga[0], mm = lgm[0];
#pragma unroll
        for (int n = 1; n < NB; ++n) { ma = fmaxf(ma, lga[n]); mm = fmaxf(mm, lgm[n]); }
        float sa = 0.f, sm = 0.f;
#pragma unroll
        for (int n = 0; n < NB; ++n) {
            aw[n] = __expf(lga[n] - ma); sa += aw[n];
            mw[n] = __expf(lgm[n] - mm); sm += mw[n];
        }
        const float ra = 1.f / sa, rm = 1.f / sm;
#pragma unroll
        for (int n = 0; n < NB; ++n) { aw[n] *= ra; mw[n] *= rm; }
    }

    // combine straight from registers — V read from HBM exactly once
    float oa[PER], om[PER];
#pragma unroll
    for (int j = 0; j < PER; ++j) { oa[j] = 0.f; om[j] = 0.f; }
#pragma unroll
    for (int n = 0; n < NB; ++n) {
#pragma unroll
        for (int j = 0; j < PER; ++j) {
            oa[j] += aw[n] * v[n][j];
            om[j] += mw[n] * v[n][j];
        }
    }

    float* outa = out + rowOff;
    float* outm = out + nStride + rowOff;
    *reinterpret_cast<float4*>(outa)     = make_float4(oa[0], oa[1], oa[2], oa[3]);
    *reinterpret_cast<float4*>(outa + 4) = make_float4(oa[4], oa[5], oa[6], oa[7]);
    *reinterpret_cast<float4*>(outm)     = make_float4(om[0], om[1], om[2], om[3]);
    *reinterpret_cast<float4*>(outm + 4) = make_float4(om[4], om[5], om[6], om[7]);
}

extern "C" void kernel_launch(void* const* d_in, const int* in_sizes, int n_in,
                              void* d_out, int out_size, void* d_ws, size_t ws_size,
                              hipStream_t stream)
{
    const float* blocks  = (const float*)d_in[0];
    const float* partial = (const float*)d_in[1];
    const float* qa      = (const float*)d_in[2];
    const float* qm      = (const float*)d_in[3];
    const float* wa      = (const float*)d_in[4];
    const float* wm      = (const float*)d_in[5];
    float* out = (float*)d_out;

    const int D  = in_sizes[2];          // 2048
    const int BT = in_sizes[1] / D;      // B*T = 8192

    dim3 grid(BT), block(THREADS);
    hipLaunchKernelGGL(block_attn_res_kernel, grid, block, 0, stream,
                       blocks, partial, qa, qm, wa, wm, out, BT);
}

// Round 2
// 132.146 us; speedup vs baseline: 1.0248x; 1.0248x over previous
//
#include <hip/hip_runtime.h>

#define NB 8          // 7 full blocks + 1 partial block
#define DDIM 2048
#define THREADS 256
#define PER 8         // DDIM / THREADS

__global__ __launch_bounds__(THREADS, 4)   // cap at 128 VGPR -> 4 blocks/CU
void block_attn_res_kernel(
    const float* __restrict__ blocks,   // [7, B*T, D]
    const float* __restrict__ partial,  // [B*T, D]
    const float* __restrict__ qa,       // [D]
    const float* __restrict__ qm,       // [D]
    const float* __restrict__ wa,       // [D]
    const float* __restrict__ wm,       // [D]
    float* __restrict__ out,            // h_attn [B*T*D] then h_mlp [B*T*D]
    int BT)
{
    const int row = blockIdx.x;
    const int tid = threadIdx.x;
    const int d0  = tid * PER;

    const size_t rowOff  = (size_t)row * DDIM + d0;
    const size_t nStride = (size_t)BT * DDIM;

    // per-thread q*w slice, kept as float4 pairs (16 VGPR)
    float4 qwa[2], qwm[2];
#pragma unroll
    for (int k = 0; k < 2; ++k) {
        const float4 q4a = *reinterpret_cast<const float4*>(qa + d0 + 4 * k);
        const float4 w4a = *reinterpret_cast<const float4*>(wa + d0 + 4 * k);
        const float4 q4m = *reinterpret_cast<const float4*>(qm + d0 + 4 * k);
        const float4 w4m = *reinterpret_cast<const float4*>(wm + d0 + 4 * k);
        qwa[k] = make_float4(q4a.x * w4a.x, q4a.y * w4a.y, q4a.z * w4a.z, q4a.w * w4a.w);
        qwm[k] = make_float4(q4m.x * w4m.x, q4m.y * w4m.y, q4m.z * w4m.z, q4m.w * w4m.w);
    }

    // register-resident V slice: 8 n-rows x 8 floats = 64 VGPR
    float4 v[NB][2];
    float ss[NB], da[NB], dm[NB];

#pragma unroll
    for (int n = 0; n < NB; ++n) {
        const float* src = (n < NB - 1) ? (blocks + (size_t)n * nStride + rowOff)
                                        : (partial + rowOff);
        v[n][0] = *reinterpret_cast<const float4*>(src);
        v[n][1] = *reinterpret_cast<const float4*>(src + 4);
        float s = 0.f, pa = 0.f, pm = 0.f;
#pragma unroll
        for (int k = 0; k < 2; ++k) {
            s  += v[n][k].x * v[n][k].x + v[n][k].y * v[n][k].y
                + v[n][k].z * v[n][k].z + v[n][k].w * v[n][k].w;
            pa += qwa[k].x * v[n][k].x + qwa[k].y * v[n][k].y
                + qwa[k].z * v[n][k].z + qwa[k].w * v[n][k].w;
            pm += qwm[k].x * v[n][k].x + qwm[k].y * v[n][k].y
                + qwm[k].z * v[n][k].z + qwm[k].w * v[n][k].w;
        }
        ss[n] = s; da[n] = pa; dm[n] = pm;
    }

    // 64-lane wave reduction of the 24 partials
#pragma unroll
    for (int n = 0; n < NB; ++n) {
#pragma unroll
        for (int off = 32; off > 0; off >>= 1) {
            ss[n] += __shfl_down(ss[n], off, 64);
            da[n] += __shfl_down(da[n], off, 64);
            dm[n] += __shfl_down(dm[n], off, 64);
        }
    }

    // cross-wave combine via tiny LDS
    __shared__ float red[THREADS / 64][NB * 3];
    const int wave = tid >> 6;
    const int lane = tid & 63;
    if (lane == 0) {
#pragma unroll
        for (int n = 0; n < NB; ++n) {
            red[wave][n]          = ss[n];
            red[wave][NB + n]     = da[n];
            red[wave][2 * NB + n] = dm[n];
        }
    }
    __syncthreads();

    float aw[NB], mw[NB];
    {
        const float inv_sqrt_d = rsqrtf((float)DDIM);
        float lga[NB], lgm[NB];
#pragma unroll
        for (int n = 0; n < NB; ++n) {
            float s  = red[0][n] + red[1][n] + red[2][n] + red[3][n];
            float pa = red[0][NB + n] + red[1][NB + n] + red[2][NB + n] + red[3][NB + n];
            float pm = red[0][2 * NB + n] + red[1][2 * NB + n] + red[2][2 * NB + n] + red[3][2 * NB + n];
            float rms = rsqrtf(s * (1.0f / DDIM) + 1e-6f);
            lga[n] = pa * rms * inv_sqrt_d;
            lgm[n] = pm * rms * inv_sqrt_d;
        }
        float ma = lga[0], mm = lgm[0];
#pragma unroll
        for (int n = 1; n < NB; ++n) { ma = fmaxf(ma, lga[n]); mm = fmaxf(mm, lgm[n]); }
        float sa = 0.f, sm = 0.f;
#pragma unroll
        for (int n = 0; n < NB; ++n) {
            aw[n] = __expf(lga[n] - ma); sa += aw[n];
            mw[n] = __expf(lgm[n] - mm); sm += mw[n];
        }
        const float ra = 1.f / sa, rm = 1.f / sm;
#pragma unroll
        for (int n = 0; n < NB; ++n) { aw[n] *= ra; mw[n] *= rm; }
    }

    // combine straight from registers — V read from HBM exactly once
    float4 oa[2], om[2];
#pragma unroll
    for (int k = 0; k < 2; ++k) {
        oa[k] = make_float4(0.f, 0.f, 0.f, 0.f);
        om[k] = make_float4(0.f, 0.f, 0.f, 0.f);
    }
#pragma unroll
    for (int n = 0; n < NB; ++n) {
#pragma unroll
        for (int k = 0; k < 2; ++k) {
            oa[k].x += aw[n] * v[n][k].x; oa[k].y += aw[n] * v[n][k].y;
            oa[k].z += aw[n] * v[n][k].z; oa[k].w += aw[n] * v[n][k].w;
            om[k].x += mw[n] * v[n][k].x; om[k].y += mw[n] * v[n][k].y;
            om[k].z += mw[n] * v[n][k].z; om[k].w += mw[n] * v[n][k].w;
        }
    }

    float* outa = out + rowOff;
    float* outm = out + nStride + rowOff;
    *reinterpret_cast<float4*>(outa)     = oa[0];
    *reinterpret_cast<float4*>(outa + 4) = oa[1];
    *reinterpret_cast<float4*>(outm)     = om[0];
    *reinterpret_cast<float4*>(outm + 4) = om[1];
}

extern "C" void kernel_launch(void* const* d_in, const int* in_sizes, int n_in,
                              void* d_out, int out_size, void* d_ws, size_t ws_size,
                              hipStream_t stream)
{
    const float* blocks  = (const float*)d_in[0];
    const float* partial = (const float*)d_in[1];
    const float* qa      = (const float*)d_in[2];
    const float* qm      = (const float*)d_in[3];
    const float* wa      = (const float*)d_in[4];
    const float* wm      = (const float*)d_in[5];
    float* out = (float*)d_out;

    const int D  = in_sizes[2];          // 2048
    const int BT = in_sizes[1] / D;      // B*T = 8192

    dim3 grid(BT), block(THREADS);
    hipLaunchKernelGGL(block_attn_res_kernel, grid, block, 0, stream,
                       blocks, partial, qa, qm, wa, wm, out, BT);
}